// Round 1
// baseline (575.901 us; speedup 1.0000x reference)
//
#include <hip/hip_runtime.h>
#include <hip/hip_bf16.h>

typedef __attribute__((ext_vector_type(8))) short short8;
typedef __attribute__((ext_vector_type(4))) float f32x4;

#define DEV __device__ __forceinline__

DEV float bf2f(ushort u){ union { float f; unsigned int i; } x; x.i = ((unsigned int)u)<<16; return x.f; }
DEV ushort f2bf(float f){ union { float fl; unsigned int i; } x; x.fl = f; unsigned int r = x.i + 0x7fffu + ((x.i>>16)&1u); return (ushort)(r>>16); }

// ---------------- fp32 -> bf16 convert ----------------
__global__ void cvt_f2b(const float* __restrict__ in, ushort* __restrict__ out, int n){
  int i = blockIdx.x*blockDim.x + threadIdx.x;
  int stride = gridDim.x*blockDim.x;
  for (; i < n; i += stride) out[i] = f2bf(in[i]);
}

// ---------------- LayerNorm over C=1024, one row per block ----------------
__global__ __launch_bounds__(256) void ln_rows(const float* __restrict__ in,
                                               const float* __restrict__ g,
                                               const float* __restrict__ bta,
                                               ushort* __restrict__ out){
  int row = blockIdx.x; int tid = threadIdx.x;
  const float* x = in + (size_t)row*1024;
  float v[4]; float s = 0.f;
  #pragma unroll
  for (int i=0;i<4;i++){ v[i] = x[tid + 256*i]; s += v[i]; }
  __shared__ float rbuf[256];
  rbuf[tid] = s; __syncthreads();
  for (int off=128; off>0; off>>=1){ if (tid<off) rbuf[tid]+=rbuf[tid+off]; __syncthreads(); }
  float mean = rbuf[0] * (1.f/1024.f);
  __syncthreads();
  float s2 = 0.f;
  #pragma unroll
  for (int i=0;i<4;i++){ float d=v[i]-mean; s2 += d*d; }
  rbuf[tid] = s2; __syncthreads();
  for (int off=128; off>0; off>>=1){ if (tid<off) rbuf[tid]+=rbuf[tid+off]; __syncthreads(); }
  float var = rbuf[0] * (1.f/1024.f);
  float rstd = rsqrtf(var + 1e-5f);
  #pragma unroll
  for (int i=0;i<4;i++){ int c = tid+256*i; out[(size_t)row*1024+c] = f2bf((v[i]-mean)*rstd*g[c]+bta[c]); }
}

// ---------------- tiny time-embedding GEMM: tq[b][j] = t[b]@time_w[:,j]+time_b[j] ----------------
__global__ __launch_bounds__(256) void tq_gemm(const float* __restrict__ t, const float* __restrict__ tw,
                                               const float* __restrict__ tb, float* __restrict__ tq){
  int j = blockIdx.x*256 + threadIdx.x;   // 0..3071
  for (int b=0;b<4;b++){
    float s = tb[j];
    for (int k=0;k<256;k++) s = fmaf(t[b*256+k], tw[(size_t)k*3072 + j], s);
    tq[b*3072 + j] = s;
  }
}

// ---------------- 128x128-tile bf16 MFMA GEMM with epilogues ----------------
// EPI 0: out_bf16 = acc + bias[col] + extra[(row>>10)*N + col]      (QKV, extra=tqkv)
// EPI 1: out_f32  = acc + bias[col] + extra[row*N + col]            (residual add)
// EPI 2: out_bf16 = gelu(acc + bias[col])                           (FF1, exact erf gelu)
template<int EPI>
__global__ __launch_bounds__(256) void gemm_epi(
    const ushort* __restrict__ A, const ushort* __restrict__ B,
    const float* __restrict__ bias, const float* __restrict__ extra,
    ushort* __restrict__ outb, float* __restrict__ outf,
    int M, int N, int K)
{
  __shared__ __align__(16) ushort Al[128][32];
  __shared__ __align__(16) ushort Bl[32][128];
  const int n0 = blockIdx.x*128, m0 = blockIdx.y*128;
  const int tid = threadIdx.x, lane = tid & 63, wid = tid >> 6;
  const int wm = (wid&1)*64, wn = (wid>>1)*64;
  const int l15 = lane&15, l4 = lane>>4;
  f32x4 acc[4][4];
  #pragma unroll
  for (int i=0;i<4;i++)
    #pragma unroll
    for (int jx=0;jx<4;jx++){ acc[i][jx][0]=0.f; acc[i][jx][1]=0.f; acc[i][jx][2]=0.f; acc[i][jx][3]=0.f; }
  const int ar = tid>>1, ac = (tid&1)*16;
  const int bkr = tid>>3, bc = (tid&7)*16;
  for (int k0=0; k0<K; k0+=32){
    const ushort* as = A + (size_t)(m0+ar)*K + k0 + ac;
    *(int4*)&Al[ar][ac]   = *(const int4*)as;
    *(int4*)&Al[ar][ac+8] = *(const int4*)(as+8);
    const ushort* bs = B + (size_t)(k0+bkr)*N + n0 + bc;
    *(int4*)&Bl[bkr][bc]   = *(const int4*)bs;
    *(int4*)&Bl[bkr][bc+8] = *(const int4*)(bs+8);
    __syncthreads();
    short8 af[4];
    #pragma unroll
    for (int mi=0;mi<4;mi++) af[mi] = *(const short8*)&Al[wm + mi*16 + l15][l4*8];
    #pragma unroll
    for (int nj=0;nj<4;nj++){
      union { ushort u[8]; short8 v; } bfr;
      #pragma unroll
      for (int i=0;i<8;i++) bfr.u[i] = Bl[l4*8+i][wn + nj*16 + l15];
      #pragma unroll
      for (int mi=0;mi<4;mi++)
        acc[mi][nj] = __builtin_amdgcn_mfma_f32_16x16x32_bf16(af[mi], bfr.v, acc[mi][nj], 0,0,0);
    }
    __syncthreads();
  }
  #pragma unroll
  for (int mi=0;mi<4;mi++)
    #pragma unroll
    for (int nj=0;nj<4;nj++)
      #pragma unroll
      for (int j=0;j<4;j++){
        int row = m0 + wm + mi*16 + l4*4 + j;
        int col = n0 + wn + nj*16 + l15;
        float v = acc[mi][nj][j] + bias[col];
        if constexpr (EPI==0){ v += extra[(size_t)(row>>10)*N + col]; outb[(size_t)row*N+col] = f2bf(v); }
        else if constexpr (EPI==1){ v += extra[(size_t)row*N + col]; outf[(size_t)row*N+col] = v; }
        else { v = 0.5f*v*(1.f+erff(v*0.70710678118f)); outb[(size_t)row*N+col] = f2bf(v); }
      }
}

// ---------------- fused rel-position attention ----------------
// grid: (b*16+h)*64 + row_tile ; 16 query rows per WG, 4 waves split the 16 column tiles.
// skew[r,c] = RR[r][c-r+1023] (c<=r) ; 0 (c==r+1) ; RR[r+1][c-r-2] (c>=r+2); RR = Q@Er^T
__global__ __launch_bounds__(256) void attn_fused(
    const ushort* __restrict__ qkv, const ushort* __restrict__ Er, ushort* __restrict__ out)
{
  const int bid = blockIdx.x;
  const int rt = bid & 63, h = (bid>>6)&15, b = bid>>10;
  const int r0 = rt*16;
  const int tid = threadIdx.x, w = tid>>6, lane = tid&63;
  const int l15 = lane&15, l4 = lane>>4;

  __shared__ __align__(16) ushort RR[17][1024];
  __shared__ __align__(16) ushort P_lds[4][16][64];
  __shared__ float Obuf[4][16][64];
  __shared__ float mlbuf[4][2][16];

  const size_t base = (size_t)b*1024*3072 + (size_t)h*64;
  const ushort* Qp = qkv + base;
  const ushort* Kp = qkv + base + 1024;
  const ushort* Vp = qkv + base + 2048;

  // Phase 1: RR rows r0..r0+16 (17 rows) x 1024 Er-indices; wave w does e-tiles [w*16, w*16+16)
  for (int t=0; t<16; ++t){
    int et = w*16 + t;
    f32x4 a0 = {0.f,0.f,0.f,0.f}, a1 = {0.f,0.f,0.f,0.f};
    #pragma unroll
    for (int ks=0; ks<2; ++ks){
      short8 bfr = *(const short8*)(Er + (size_t)(et*16 + l15)*64 + ks*32 + l4*8);
      short8 af0 = *(const short8*)(Qp + (size_t)(r0 + l15)*3072 + ks*32 + l4*8);
      int q1 = r0 + 16 + l15; if (q1 > 1023) q1 = 1023;   // last tile: row 1024 never consumed
      short8 af1 = *(const short8*)(Qp + (size_t)q1*3072 + ks*32 + l4*8);
      a0 = __builtin_amdgcn_mfma_f32_16x16x32_bf16(af0, bfr, a0, 0,0,0);
      a1 = __builtin_amdgcn_mfma_f32_16x16x32_bf16(af1, bfr, a1, 0,0,0);
    }
    #pragma unroll
    for (int j=0;j<4;j++) RR[l4*4+j][et*16 + l15] = f2bf(a0[j]);
    if (l4 == 0) RR[16][et*16 + l15] = f2bf(a1[0]);
  }
  __syncthreads();

  // Q fragments for this WG's 16 rows
  short8 qa[2];
  #pragma unroll
  for (int ks=0; ks<2; ++ks)
    qa[ks] = *(const short8*)(Qp + (size_t)(r0 + l15)*3072 + ks*32 + l4*8);

  float mrow[4], lrow[4], scl[4];
  f32x4 Oacc[4];
  #pragma unroll
  for (int j=0;j<4;j++){ mrow[j] = -1e30f; lrow[j] = 0.f; }
  #pragma unroll
  for (int n2=0;n2<4;n2++){ Oacc[n2][0]=0.f; Oacc[n2][1]=0.f; Oacc[n2][2]=0.f; Oacc[n2][3]=0.f; }

  // Phase 2: online softmax over this wave's 4 column tiles of 64
  for (int t=0;t<4;++t){
    int c0 = (w*4 + t)*64;
    f32x4 S[4];
    #pragma unroll
    for (int nt=0;nt<4;nt++){ S[nt][0]=0.f; S[nt][1]=0.f; S[nt][2]=0.f; S[nt][3]=0.f; }
    #pragma unroll
    for (int nt=0; nt<4; ++nt)
      #pragma unroll
      for (int ks=0; ks<2; ++ks){
        short8 kb = *(const short8*)(Kp + (size_t)(c0 + nt*16 + l15)*3072 + ks*32 + l4*8);
        S[nt] = __builtin_amdgcn_mfma_f32_16x16x32_bf16(qa[ks], kb, S[nt], 0,0,0);
      }
    float tmax[4];
    #pragma unroll
    for (int j=0;j<4;j++) tmax[j] = -3e38f;
    #pragma unroll
    for (int nt=0;nt<4;nt++)
      #pragma unroll
      for (int j=0;j<4;j++){
        int lr = l4*4 + j;
        int row = r0 + lr;
        int col = c0 + nt*16 + l15;
        int d = col - row;
        float sk;
        if (d <= 0)      sk = bf2f(RR[lr][col - row + 1023]);
        else if (d == 1) sk = 0.f;
        else             sk = bf2f(RR[lr+1][col - row - 2]);
        float v = S[nt][j]*0.125f + sk;
        S[nt][j] = v;
        tmax[j] = fmaxf(tmax[j], v);
      }
    #pragma unroll
    for (int j=0;j<4;j++){
      #pragma unroll
      for (int off=1; off<16; off<<=1) tmax[j] = fmaxf(tmax[j], __shfl_xor(tmax[j], off, 64));
      float mn = fmaxf(mrow[j], tmax[j]);
      scl[j] = __expf(mrow[j] - mn);
      mrow[j] = mn;
    }
    float tsum[4] = {0.f,0.f,0.f,0.f};
    #pragma unroll
    for (int nt=0;nt<4;nt++)
      #pragma unroll
      for (int j=0;j<4;j++){
        float p = __expf(S[nt][j] - mrow[j]);
        tsum[j] += p;
        P_lds[w][l4*4+j][nt*16 + l15] = f2bf(p);
      }
    #pragma unroll
    for (int j=0;j<4;j++){
      #pragma unroll
      for (int off=1; off<16; off<<=1) tsum[j] += __shfl_xor(tsum[j], off, 64);
      lrow[j] = lrow[j]*scl[j] + tsum[j];
    }
    #pragma unroll
    for (int n2=0;n2<4;n2++)
      #pragma unroll
      for (int j=0;j<4;j++) Oacc[n2][j] *= scl[j];
    __syncthreads();   // P_lds visible (per-wave buffer; barrier keeps waves aligned)
    #pragma unroll
    for (int ks=0; ks<2; ++ks){
      short8 pa = *(const short8*)&P_lds[w][l15][ks*32 + l4*8];
      #pragma unroll
      for (int n2=0; n2<4; ++n2){
        union { ushort u[8]; short8 v; } vb;
        #pragma unroll
        for (int i=0;i<8;i++) vb.u[i] = Vp[(size_t)(c0 + ks*32 + l4*8 + i)*3072 + n2*16 + l15];
        Oacc[n2] = __builtin_amdgcn_mfma_f32_16x16x32_bf16(pa, vb.v, Oacc[n2], 0,0,0);
      }
    }
    __syncthreads();   // P reads done before next tile overwrites
  }

  // Phase 3: merge the 4 waves' partial (m, l, O)
  #pragma unroll
  for (int n2=0;n2<4;n2++)
    #pragma unroll
    for (int j=0;j<4;j++) Obuf[w][l4*4+j][n2*16+l15] = Oacc[n2][j];
  if (l15 == 0){
    #pragma unroll
    for (int j=0;j<4;j++){ mlbuf[w][0][l4*4+j] = mrow[j]; mlbuf[w][1][l4*4+j] = lrow[j]; }
  }
  __syncthreads();
  {
    int row = tid>>4, cb = (tid&15)*4;
    float M = mlbuf[0][0][row];
    for (int w2=1;w2<4;w2++) M = fmaxf(M, mlbuf[w2][0][row]);
    float den = 0.f, num[4] = {0.f,0.f,0.f,0.f};
    for (int w2=0;w2<4;w2++){
      float e = __expf(mlbuf[w2][0][row] - M);
      den += mlbuf[w2][1][row]*e;
      #pragma unroll
      for (int i=0;i<4;i++) num[i] += Obuf[w2][row][cb+i]*e;
    }
    float inv = 1.f/den;
    size_t o = ((size_t)(b*1024 + r0 + row))*1024 + h*64 + cb;
    #pragma unroll
    for (int i=0;i<4;i++) out[o+i] = f2bf(num[i]*inv);
  }
}

extern "C" void kernel_launch(void* const* d_in, const int* in_sizes, int n_in,
                              void* d_out, int out_size, void* d_ws, size_t ws_size,
                              hipStream_t stream)
{
  const float* x    = (const float*)d_in[0];
  const float* t    = (const float*)d_in[1];
  const float* ln1g = (const float*)d_in[2];
  const float* ln1b = (const float*)d_in[3];
  const float* qkvw = (const float*)d_in[4];
  const float* qkvb = (const float*)d_in[5];
  const float* timew= (const float*)d_in[6];
  const float* timeb= (const float*)d_in[7];
  const float* outw = (const float*)d_in[8];
  const float* outbv= (const float*)d_in[9];
  const float* Er   = (const float*)d_in[10];
  const float* ln2g = (const float*)d_in[11];
  const float* ln2b = (const float*)d_in[12];
  const float* ff1w = (const float*)d_in[13];
  const float* ff1b = (const float*)d_in[14];
  const float* ff2w = (const float*)d_in[15];
  const float* ff2b = (const float*)d_in[16];
  float* o = (float*)d_out;

  char* ws = (char*)d_ws;
  ushort* qkvw_b = (ushort*)(ws);              // 1024x3072 bf16
  ushort* outw_b = (ushort*)(ws + 6291456);    // 1024x1024
  ushort* ff1w_b = (ushort*)(ws + 8388608);    // 1024x4096
  ushort* ff2w_b = (ushort*)(ws + 16777216);   // 4096x1024
  ushort* er_b   = (ushort*)(ws + 25165824);   // 1024x64
  float*  tq     = (float*) (ws + 25296896);   // 4x3072 f32
  ushort* bufA   = (ushort*)(ws + 25346048);   // 4096x1024 bf16: xn -> attn_out -> h2
  ushort* bufB   = (ushort*)(ws + 33734656);   // up to 4096x4096 bf16: qkv -> ff1o
  // total ws usage: 67,289,088 bytes

  cvt_f2b<<<2048,256,0,stream>>>(qkvw, qkvw_b, 3145728);
  cvt_f2b<<<1024,256,0,stream>>>(outw, outw_b, 1048576);
  cvt_f2b<<<2048,256,0,stream>>>(ff1w, ff1w_b, 4194304);
  cvt_f2b<<<2048,256,0,stream>>>(ff2w, ff2w_b, 4194304);
  cvt_f2b<<<256,256,0,stream>>>(Er, er_b, 65536);

  ln_rows<<<4096,256,0,stream>>>(x, ln1g, ln1b, bufA);
  tq_gemm<<<12,256,0,stream>>>(t, timew, timeb, tq);
  gemm_epi<0><<<dim3(24,32),256,0,stream>>>(bufA, qkvw_b, qkvb, tq, bufB, nullptr, 4096,3072,1024);
  attn_fused<<<4096,256,0,stream>>>(bufB, er_b, bufA);
  gemm_epi<1><<<dim3(8,32),256,0,stream>>>(bufA, outw_b, outbv, x, nullptr, o, 4096,1024,1024);
  ln_rows<<<4096,256,0,stream>>>(o, ln2g, ln2b, bufA);
  gemm_epi<2><<<dim3(32,32),256,0,stream>>>(bufA, ff1w_b, ff1b, nullptr, bufB, nullptr, 4096,4096,1024);
  gemm_epi<1><<<dim3(8,32),256,0,stream>>>(bufB, ff2w_b, ff2b, o, nullptr, o, 4096,1024,4096);
}

// Round 2
// 464.302 us; speedup vs baseline: 1.2404x; 1.2404x over previous
//
#include <hip/hip_runtime.h>
#include <hip/hip_bf16.h>

typedef __attribute__((ext_vector_type(8))) short short8;
typedef __attribute__((ext_vector_type(4))) float f32x4;

#define DEV __device__ __forceinline__

DEV float bf2f(ushort u){ union { float f; unsigned int i; } x; x.i = ((unsigned int)u)<<16; return x.f; }
DEV ushort f2bf(float f){ union { float fl; unsigned int i; } x; x.fl = f; unsigned int r = x.i + 0x7fffu + ((x.i>>16)&1u); return (ushort)(r>>16); }

// ---------------- fp32 -> bf16 convert (Er only) ----------------
__global__ void cvt_f2b(const float* __restrict__ in, ushort* __restrict__ out, int n){
  int i = blockIdx.x*blockDim.x + threadIdx.x;
  int stride = gridDim.x*blockDim.x;
  for (; i < n; i += stride) out[i] = f2bf(in[i]);
}

// ---------------- fp32 [K][N] -> bf16 [N][K] tiled transpose ----------------
__global__ __launch_bounds__(256) void wt_cvt(const float* __restrict__ in, ushort* __restrict__ out,
                                              int K, int N){
  const int n0 = blockIdx.x*64, k0 = blockIdx.y*64;
  __shared__ float T[64][65];
  const int tid = threadIdx.x;
  const int r = tid>>4, c = (tid&15)*4;
  #pragma unroll
  for (int p=0;p<4;p++){
    float4 v = *(const float4*)&in[(size_t)(k0 + p*16 + r)*N + n0 + c];
    T[p*16+r][c+0]=v.x; T[p*16+r][c+1]=v.y; T[p*16+r][c+2]=v.z; T[p*16+r][c+3]=v.w;
  }
  __syncthreads();
  #pragma unroll
  for (int p=0;p<4;p++){
    int n = p*16 + r;
    ushort u0 = f2bf(T[c+0][n]), u1 = f2bf(T[c+1][n]), u2 = f2bf(T[c+2][n]), u3 = f2bf(T[c+3][n]);
    ushort4 u = make_ushort4(u0,u1,u2,u3);
    *(ushort4*)&out[(size_t)(n0+n)*K + k0 + c] = u;
  }
}

// ---------------- V transpose: qkv V-part [n][hd] -> Vt [(bh*64+hd)][n] ----------------
__global__ __launch_bounds__(256) void vt_k(const ushort* __restrict__ qkv, ushort* __restrict__ vt){
  const int bh = blockIdx.y; const int b = bh>>4, h = bh&15;
  const int n0 = blockIdx.x*64;
  __shared__ ushort T[64][66];
  const int tid = threadIdx.x;
  const int r = tid>>3, c8 = (tid&7)*8;
  #pragma unroll
  for (int p=0;p<2;p++){
    int row = p*32 + r;
    short8 v = *(const short8*)&qkv[(size_t)(b*1024 + n0 + row)*3072 + 2048 + h*64 + c8];
    #pragma unroll
    for (int i=0;i<8;i++) T[row][c8+i] = ((ushort*)&v)[i];
  }
  __syncthreads();
  #pragma unroll
  for (int p=0;p<2;p++){
    int d = p*32 + r;
    union { ushort u[8]; short8 v; } o;
    #pragma unroll
    for (int i=0;i<8;i++) o.u[i] = T[c8+i][d];
    *(short8*)&vt[(size_t)(bh*64 + d)*1024 + n0 + c8] = o.v;
  }
}

// ---------------- LayerNorm over C=1024, one row per block ----------------
__global__ __launch_bounds__(256) void ln_rows(const float* __restrict__ in,
                                               const float* __restrict__ g,
                                               const float* __restrict__ bta,
                                               ushort* __restrict__ out){
  int row = blockIdx.x; int tid = threadIdx.x;
  const float* x = in + (size_t)row*1024;
  float v[4]; float s = 0.f;
  #pragma unroll
  for (int i=0;i<4;i++){ v[i] = x[tid + 256*i]; s += v[i]; }
  __shared__ float rbuf[256];
  rbuf[tid] = s; __syncthreads();
  for (int off=128; off>0; off>>=1){ if (tid<off) rbuf[tid]+=rbuf[tid+off]; __syncthreads(); }
  float mean = rbuf[0] * (1.f/1024.f);
  __syncthreads();
  float s2 = 0.f;
  #pragma unroll
  for (int i=0;i<4;i++){ float d=v[i]-mean; s2 += d*d; }
  rbuf[tid] = s2; __syncthreads();
  for (int off=128; off>0; off>>=1){ if (tid<off) rbuf[tid]+=rbuf[tid+off]; __syncthreads(); }
  float var = rbuf[0] * (1.f/1024.f);
  float rstd = rsqrtf(var + 1e-5f);
  #pragma unroll
  for (int i=0;i<4;i++){ int c = tid+256*i; out[(size_t)row*1024+c] = f2bf((v[i]-mean)*rstd*g[c]+bta[c]); }
}

// ---------------- time-embedding GEMM ----------------
__global__ __launch_bounds__(256) void tq_gemm2(const float* __restrict__ t, const float* __restrict__ tw,
                                                const float* __restrict__ tb, float* __restrict__ tq){
  const int tid = threadIdx.x;
  const int j = blockIdx.x*64 + (tid & 63);
  const int sl = tid >> 6;
  float acc[4] = {0.f,0.f,0.f,0.f};
  for (int k = sl*64; k < sl*64+64; ++k){
    float wv = tw[(size_t)k*3072 + j];
    #pragma unroll
    for (int b=0;b<4;b++) acc[b] = fmaf(t[b*256+k], wv, acc[b]);
  }
  __shared__ float red[4][4][64];
  #pragma unroll
  for (int b=0;b<4;b++) red[sl][b][tid&63] = acc[b];
  __syncthreads();
  if (sl == 0){
    #pragma unroll
    for (int b=0;b<4;b++)
      tq[b*3072 + j] = red[0][b][tid&63] + red[1][b][tid&63] + red[2][b][tid&63] + red[3][b][tid&63] + tb[j];
  }
}

// ---------------- 128x128-tile bf16 MFMA GEMM, BK=64, Bt is [N][K] ----------------
// EPI 0: out_bf16 = acc + bias[col] + extra[(row>>10)*N + col]      (QKV, extra=tqkv)
// EPI 1: out_f32  = acc + bias[col] + extra[row*N + col]            (residual add)
// EPI 2: out_bf16 = gelu(acc + bias[col])                           (FF1, exact erf gelu)
template<int EPI>
__global__ __launch_bounds__(256) void gemm2(
    const ushort* __restrict__ A, const ushort* __restrict__ Bt,
    const float* __restrict__ bias, const float* __restrict__ extra,
    ushort* __restrict__ outb, float* __restrict__ outf,
    int M, int N, int K)
{
  __shared__ __align__(16) ushort Al[128][72];
  __shared__ __align__(16) ushort Bl[128][72];
  const int n0 = blockIdx.x*128, m0 = blockIdx.y*128;
  const int tid = threadIdx.x, lane = tid & 63, wid = tid >> 6;
  const int wm = (wid&1)*64, wn = (wid>>1)*64;
  const int l15 = lane&15, l4 = lane>>4;
  f32x4 acc[4][4];
  #pragma unroll
  for (int i=0;i<4;i++)
    #pragma unroll
    for (int jx=0;jx<4;jx++){ acc[i][jx][0]=0.f; acc[i][jx][1]=0.f; acc[i][jx][2]=0.f; acc[i][jx][3]=0.f; }
  const int srow = tid>>1, shalf = (tid&1)*32;
  const ushort* aptr = A  + (size_t)(m0+srow)*K + shalf;
  const ushort* bptr = Bt + (size_t)(n0+srow)*K + shalf;
  for (int k0=0; k0<K; k0+=64){
    #pragma unroll
    for (int i=0;i<4;i++){
      *(short8*)&Al[srow][shalf + i*8] = *(const short8*)(aptr + k0 + i*8);
      *(short8*)&Bl[srow][shalf + i*8] = *(const short8*)(bptr + k0 + i*8);
    }
    __syncthreads();
    #pragma unroll
    for (int ks=0; ks<2; ++ks){
      short8 af[4], bfr[4];
      #pragma unroll
      for (int mi=0;mi<4;mi++) af[mi]  = *(const short8*)&Al[wm + mi*16 + l15][ks*32 + l4*8];
      #pragma unroll
      for (int nj=0;nj<4;nj++) bfr[nj] = *(const short8*)&Bl[wn + nj*16 + l15][ks*32 + l4*8];
      #pragma unroll
      for (int mi=0;mi<4;mi++)
        #pragma unroll
        for (int nj=0;nj<4;nj++)
          acc[mi][nj] = __builtin_amdgcn_mfma_f32_16x16x32_bf16(af[mi], bfr[nj], acc[mi][nj], 0,0,0);
    }
    __syncthreads();
  }
  #pragma unroll
  for (int mi=0;mi<4;mi++)
    #pragma unroll
    for (int nj=0;nj<4;nj++)
      #pragma unroll
      for (int j=0;j<4;j++){
        int row = m0 + wm + mi*16 + l4*4 + j;
        int col = n0 + wn + nj*16 + l15;
        float v = acc[mi][nj][j] + bias[col];
        if constexpr (EPI==0){ v += extra[(size_t)(row>>10)*N + col]; outb[(size_t)row*N+col] = f2bf(v); }
        else if constexpr (EPI==1){ v += extra[(size_t)row*N + col]; outf[(size_t)row*N+col] = v; }
        else { v = 0.5f*v*(1.f+erff(v*0.70710678118f)); outb[(size_t)row*N+col] = f2bf(v); }
      }
}

// ---------------- fused rel-position attention v2 (swapped-operand, barrier-free KV loop) ----------------
// grid: (b*16+h)*64 + row_tile ; 16 query rows per WG, 4 waves split the 16 kv tiles (4 each).
// S^T = mfma(K, Q): lane owns q-row = l15, kv = c0 + f*16 + l4*4 + j.
// skew via flat RRF stride 1033: off = (d<=0) ? 1024+d : 1032+d ; RRF[(lr+1)*1033] = 0 handles d==1.
__global__ __launch_bounds__(256) void attn2(
    const ushort* __restrict__ qkv, const ushort* __restrict__ Er,
    const ushort* __restrict__ Vt, ushort* __restrict__ out)
{
  const int bid = blockIdx.x;
  const int rt = bid & 63, h = (bid>>6)&15, b = bid>>10;
  const int bh = b*16 + h;
  const int r0 = rt*16;
  const int tid = threadIdx.x, w = tid>>6, lane = tid&63;
  const int l15 = lane&15, l4 = lane>>4;

  __shared__ ushort RRF[17552];              // 16*1033 + 1024 flat skew-ready rel
  __shared__ __align__(16) ushort P_l[4][16][72];
  __shared__ ushort Obuf[4][16][64];
  __shared__ float mlbuf[4][2][16];

  const size_t base = (size_t)b*1024*3072 + (size_t)h*64;
  const ushort* Qp = qkv + base;
  const ushort* Kp = qkv + base + 1024;
  const ushort* Vp = Vt + (size_t)bh*64*1024;

  if (tid < 16) RRF[(tid+1)*1033] = 0;

  // Q fragments (serve as A-frag in phase 1 and B-frag in phase 2 — same load)
  short8 qa[2], qb[2];
  const int q1 = min(r0 + 16 + l15, 1023);
  #pragma unroll
  for (int ks=0; ks<2; ++ks){
    qa[ks] = *(const short8*)(Qp + (size_t)(r0 + l15)*3072 + ks*32 + l4*8);
    qb[ks] = *(const short8*)(Qp + (size_t)q1*3072 + ks*32 + l4*8);
  }

  // Phase 1: rel rows r0..r0+16 into RRF (wave w covers e in [w*256, w*256+256))
  for (int t=0; t<16; ++t){
    const int et = w*16 + t;
    f32x4 a0 = {0.f,0.f,0.f,0.f}, a1 = {0.f,0.f,0.f,0.f};
    #pragma unroll
    for (int ks=0; ks<2; ++ks){
      short8 bfr = *(const short8*)(Er + (size_t)(et*16 + l15)*64 + ks*32 + l4*8);
      a0 = __builtin_amdgcn_mfma_f32_16x16x32_bf16(qa[ks], bfr, a0, 0,0,0);
      a1 = __builtin_amdgcn_mfma_f32_16x16x32_bf16(qb[ks], bfr, a1, 0,0,0);
    }
    const int e = et*16 + l15;
    #pragma unroll
    for (int j=0;j<4;j++) RRF[(l4*4+j)*1033 + 1 + e] = f2bf(a0[j]);
    if (l4 == 0) RRF[16*1033 + 1 + e] = f2bf(a1[0]);
  }
  __syncthreads();

  float m = -1e30f, lsum = 0.f;
  f32x4 Oacc[4];
  #pragma unroll
  for (int n2=0;n2<4;n2++){ Oacc[n2][0]=0.f; Oacc[n2][1]=0.f; Oacc[n2][2]=0.f; Oacc[n2][3]=0.f; }
  const int dl = 4*l4 - l15;          // kv-offset minus row-offset within tile
  const int rbase = l15*1033;

  // Phase 2: online softmax, wave w covers kv in [w*256, w*256+256), no barriers
  for (int t=0;t<4;++t){
    const int c0 = (w*4 + t)*64;
    f32x4 S[4];
    short8 ka[4][2];
    #pragma unroll
    for (int f=0;f<4;f++)
      #pragma unroll
      for (int ks=0;ks<2;ks++)
        ka[f][ks] = *(const short8*)(Kp + (size_t)(c0 + f*16 + l15)*3072 + ks*32 + l4*8);
    #pragma unroll
    for (int f=0;f<4;f++){
      S[f][0]=0.f; S[f][1]=0.f; S[f][2]=0.f; S[f][3]=0.f;
      #pragma unroll
      for (int ks=0;ks<2;ks++)
        S[f] = __builtin_amdgcn_mfma_f32_16x16x32_bf16(ka[f][ks], qa[ks], S[f], 0,0,0);
    }
    // scale + skew add + row max (row = l15, per-lane)
    float tmax = -3e30f;
    #pragma unroll
    for (int f=0;f<4;f++)
      #pragma unroll
      for (int j=0;j<4;j++){
        int d = (c0 + f*16 + j - r0) + dl;
        int off = (d<=0) ? (1024+d) : (1032+d);
        float sk = bf2f(RRF[rbase + off]);
        float v = S[f][j]*0.125f + sk;
        S[f][j] = v;
        tmax = fmaxf(tmax, v);
      }
    tmax = fmaxf(tmax, __shfl_xor(tmax, 16, 64));
    tmax = fmaxf(tmax, __shfl_xor(tmax, 32, 64));
    const float mn = fmaxf(m, tmax);
    const float scl = __expf(m - mn);
    m = mn;
    float tsum = 0.f;
    #pragma unroll
    for (int f=0;f<4;f++)
      #pragma unroll
      for (int j=0;j<4;j++){
        float p = __expf(S[f][j] - m);
        tsum += p;
        P_l[w][l15][f*16 + l4*4 + j] = f2bf(p);
      }
    tsum += __shfl_xor(tsum, 16, 64);
    tsum += __shfl_xor(tsum, 32, 64);
    lsum = lsum*scl + tsum;
    #pragma unroll
    for (int n2=0;n2<4;n2++)
      #pragma unroll
      for (int j=0;j<4;j++) Oacc[n2][j] *= scl;
    // PV: O^T = mfma(V^T, P^T); per-wave P_l, no barrier needed (same-wave ds dependency)
    #pragma unroll
    for (int ks=0; ks<2; ++ks){
      short8 pb = *(const short8*)&P_l[w][l15][ks*32 + l4*8];
      #pragma unroll
      for (int n2=0; n2<4; ++n2){
        short8 va = *(const short8*)(Vp + (size_t)(n2*16 + l15)*1024 + c0 + ks*32 + l4*8);
        Oacc[n2] = __builtin_amdgcn_mfma_f32_16x16x32_bf16(va, pb, Oacc[n2], 0,0,0);
      }
    }
  }

  // Merge the 4 waves' partials (each wave has all 16 rows over its kv quarter)
  #pragma unroll
  for (int n2=0;n2<4;n2++)
    #pragma unroll
    for (int j=0;j<4;j++) Obuf[w][l15][n2*16 + l4*4 + j] = f2bf(Oacc[n2][j]);
  if (l4 == 0){ mlbuf[w][0][l15] = m; mlbuf[w][1][l15] = lsum; }
  __syncthreads();
  {
    const int row = tid>>4, hb = (tid&15)*4;
    float M2 = mlbuf[0][0][row];
    #pragma unroll
    for (int w2=1;w2<4;w2++) M2 = fmaxf(M2, mlbuf[w2][0][row]);
    float den = 0.f, num[4] = {0.f,0.f,0.f,0.f};
    #pragma unroll
    for (int w2=0;w2<4;w2++){
      float e = __expf(mlbuf[w2][0][row] - M2);
      den += mlbuf[w2][1][row]*e;
      #pragma unroll
      for (int i=0;i<4;i++) num[i] += bf2f(Obuf[w2][row][hb+i])*e;
    }
    float inv = 1.f/den;
    ushort4 u;
    u.x = f2bf(num[0]*inv); u.y = f2bf(num[1]*inv); u.z = f2bf(num[2]*inv); u.w = f2bf(num[3]*inv);
    *(ushort4*)&out[((size_t)(b*1024 + r0 + row))*1024 + h*64 + hb] = u;
  }
}

extern "C" void kernel_launch(void* const* d_in, const int* in_sizes, int n_in,
                              void* d_out, int out_size, void* d_ws, size_t ws_size,
                              hipStream_t stream)
{
  const float* x    = (const float*)d_in[0];
  const float* t    = (const float*)d_in[1];
  const float* ln1g = (const float*)d_in[2];
  const float* ln1b = (const float*)d_in[3];
  const float* qkvw = (const float*)d_in[4];
  const float* qkvb = (const float*)d_in[5];
  const float* timew= (const float*)d_in[6];
  const float* timeb= (const float*)d_in[7];
  const float* outw = (const float*)d_in[8];
  const float* outbv= (const float*)d_in[9];
  const float* Er   = (const float*)d_in[10];
  const float* ln2g = (const float*)d_in[11];
  const float* ln2b = (const float*)d_in[12];
  const float* ff1w = (const float*)d_in[13];
  const float* ff1b = (const float*)d_in[14];
  const float* ff2w = (const float*)d_in[15];
  const float* ff2b = (const float*)d_in[16];
  float* o = (float*)d_out;

  char* ws = (char*)d_ws;
  ushort* qkvw_t = (ushort*)(ws);              // [3072][1024]
  ushort* outw_t = (ushort*)(ws + 6291456);    // [1024][1024]
  ushort* ff1w_t = (ushort*)(ws + 8388608);    // [4096][1024]
  ushort* ff2w_t = (ushort*)(ws + 16777216);   // [1024][4096]
  ushort* er_b   = (ushort*)(ws + 25165824);   // [1024][64]
  float*  tq     = (float*) (ws + 25296896);   // [4][3072]
  ushort* bufA   = (ushort*)(ws + 25346048);   // 4096x1024 bf16: xn -> attn_out -> h
  ushort* vt     = (ushort*)(ws + 33734656);   // [64*64][1024] bf16 V-transposed
  ushort* bufB   = (ushort*)(ws + 42123264);   // qkv 4096x3072 / ff1o 4096x4096
  // total ws usage: 75,677,696 bytes

  wt_cvt<<<dim3(48,16),256,0,stream>>>(qkvw, qkvw_t, 1024, 3072);
  wt_cvt<<<dim3(16,16),256,0,stream>>>(outw, outw_t, 1024, 1024);
  wt_cvt<<<dim3(64,16),256,0,stream>>>(ff1w, ff1w_t, 1024, 4096);
  wt_cvt<<<dim3(16,64),256,0,stream>>>(ff2w, ff2w_t, 4096, 1024);
  cvt_f2b<<<256,256,0,stream>>>(Er, er_b, 65536);

  ln_rows<<<4096,256,0,stream>>>(x, ln1g, ln1b, bufA);
  tq_gemm2<<<48,256,0,stream>>>(t, timew, timeb, tq);
  gemm2<0><<<dim3(24,32),256,0,stream>>>(bufA, qkvw_t, qkvb, tq, bufB, nullptr, 4096,3072,1024);
  vt_k<<<dim3(16,64),256,0,stream>>>(bufB, vt);
  attn2<<<4096,256,0,stream>>>(bufB, er_b, vt, bufA);
  gemm2<1><<<dim3(8,32),256,0,stream>>>(bufA, outw_t, outbv, x, nullptr, o, 4096,1024,1024);
  ln_rows<<<4096,256,0,stream>>>(o, ln2g, ln2b, bufA);
  gemm2<2><<<dim3(32,32),256,0,stream>>>(bufA, ff1w_t, ff1b, nullptr, bufB, nullptr, 4096,4096,1024);
  gemm2<1><<<dim3(8,32),256,0,stream>>>(bufB, ff2w_t, ff2b, o, nullptr, o, 4096,1024,4096);
}

// Round 3
// 458.183 us; speedup vs baseline: 1.2569x; 1.0134x over previous
//
#include <hip/hip_runtime.h>
#include <hip/hip_bf16.h>

typedef __attribute__((ext_vector_type(8))) short short8;
typedef __attribute__((ext_vector_type(4))) float f32x4;

#define DEV __device__ __forceinline__

DEV float bf2f(ushort u){ union { float f; unsigned int i; } x; x.i = ((unsigned int)u)<<16; return x.f; }
DEV ushort f2bf(float f){ union { float fl; unsigned int i; } x; x.fl = f; unsigned int r = x.i + 0x7fffu + ((x.i>>16)&1u); return (ushort)(r>>16); }

DEV void gl2lds16(const ushort* g, ushort* l){
  __builtin_amdgcn_global_load_lds((const __attribute__((address_space(1))) void*)g,
                                   (__attribute__((address_space(3))) void*)l, 16, 0, 0);
}

// ---------------- fp32 -> bf16 convert (Er only) ----------------
__global__ void cvt_f2b(const float* __restrict__ in, ushort* __restrict__ out, int n){
  int i = blockIdx.x*blockDim.x + threadIdx.x;
  int stride = gridDim.x*blockDim.x;
  for (; i < n; i += stride) out[i] = f2bf(in[i]);
}

// ---------------- fp32 [K][N] -> bf16 [N][K] tiled transpose ----------------
__global__ __launch_bounds__(256) void wt_cvt(const float* __restrict__ in, ushort* __restrict__ out,
                                              int K, int N){
  const int n0 = blockIdx.x*64, k0 = blockIdx.y*64;
  __shared__ float T[64][65];
  const int tid = threadIdx.x;
  const int r = tid>>4, c = (tid&15)*4;
  #pragma unroll
  for (int p=0;p<4;p++){
    float4 v = *(const float4*)&in[(size_t)(k0 + p*16 + r)*N + n0 + c];
    T[p*16+r][c+0]=v.x; T[p*16+r][c+1]=v.y; T[p*16+r][c+2]=v.z; T[p*16+r][c+3]=v.w;
  }
  __syncthreads();
  #pragma unroll
  for (int p=0;p<4;p++){
    int n = p*16 + r;
    ushort u0 = f2bf(T[c+0][n]), u1 = f2bf(T[c+1][n]), u2 = f2bf(T[c+2][n]), u3 = f2bf(T[c+3][n]);
    ushort4 u = make_ushort4(u0,u1,u2,u3);
    *(ushort4*)&out[(size_t)(n0+n)*K + k0 + c] = u;
  }
}

// ---------------- V transpose: qkv V-part [n][hd] -> Vt [(bh*64+hd)][n] ----------------
__global__ __launch_bounds__(256) void vt_k(const ushort* __restrict__ qkv, ushort* __restrict__ vt){
  const int bh = blockIdx.y; const int b = bh>>4, h = bh&15;
  const int n0 = blockIdx.x*64;
  __shared__ ushort T[64][66];
  const int tid = threadIdx.x;
  const int r = tid>>3, c8 = (tid&7)*8;
  #pragma unroll
  for (int p=0;p<2;p++){
    int row = p*32 + r;
    short8 v = *(const short8*)&qkv[(size_t)(b*1024 + n0 + row)*3072 + 2048 + h*64 + c8];
    #pragma unroll
    for (int i=0;i<8;i++) T[row][c8+i] = ((ushort*)&v)[i];
  }
  __syncthreads();
  #pragma unroll
  for (int p=0;p<2;p++){
    int d = p*32 + r;
    union { ushort u[8]; short8 v; } o;
    #pragma unroll
    for (int i=0;i<8;i++) o.u[i] = T[c8+i][d];
    *(short8*)&vt[(size_t)(bh*64 + d)*1024 + n0 + c8] = o.v;
  }
}

// ---------------- LayerNorm over C=1024, one row per block ----------------
__global__ __launch_bounds__(256) void ln_rows(const float* __restrict__ in,
                                               const float* __restrict__ g,
                                               const float* __restrict__ bta,
                                               ushort* __restrict__ out){
  int row = blockIdx.x; int tid = threadIdx.x;
  const float* x = in + (size_t)row*1024;
  float v[4]; float s = 0.f;
  #pragma unroll
  for (int i=0;i<4;i++){ v[i] = x[tid + 256*i]; s += v[i]; }
  __shared__ float rbuf[256];
  rbuf[tid] = s; __syncthreads();
  for (int off=128; off>0; off>>=1){ if (tid<off) rbuf[tid]+=rbuf[tid+off]; __syncthreads(); }
  float mean = rbuf[0] * (1.f/1024.f);
  __syncthreads();
  float s2 = 0.f;
  #pragma unroll
  for (int i=0;i<4;i++){ float d=v[i]-mean; s2 += d*d; }
  rbuf[tid] = s2; __syncthreads();
  for (int off=128; off>0; off>>=1){ if (tid<off) rbuf[tid]+=rbuf[tid+off]; __syncthreads(); }
  float var = rbuf[0] * (1.f/1024.f);
  float rstd = rsqrtf(var + 1e-5f);
  #pragma unroll
  for (int i=0;i<4;i++){ int c = tid+256*i; out[(size_t)row*1024+c] = f2bf((v[i]-mean)*rstd*g[c]+bta[c]); }
}

// ---------------- time-embedding GEMM ----------------
__global__ __launch_bounds__(256) void tq_gemm2(const float* __restrict__ t, const float* __restrict__ tw,
                                                const float* __restrict__ tb, float* __restrict__ tq){
  const int tid = threadIdx.x;
  const int j = blockIdx.x*64 + (tid & 63);
  const int sl = tid >> 6;
  float acc[4] = {0.f,0.f,0.f,0.f};
  for (int k = sl*64; k < sl*64+64; ++k){
    float wv = tw[(size_t)k*3072 + j];
    #pragma unroll
    for (int b=0;b<4;b++) acc[b] = fmaf(t[b*256+k], wv, acc[b]);
  }
  __shared__ float red[4][4][64];
  #pragma unroll
  for (int b=0;b<4;b++) red[sl][b][tid&63] = acc[b];
  __syncthreads();
  if (sl == 0){
    #pragma unroll
    for (int b=0;b<4;b++)
      tq[b*3072 + j] = red[0][b][tid&63] + red[1][b][tid&63] + red[2][b][tid&63] + red[3][b][tid&63] + tb[j];
  }
}

// ---------------- m97-style 128x128 GEMM: BK=32, linear LDS, global_load_lds, XCD swizzle ----------------
template<int EPI>
__global__ __launch_bounds__(256) void gemm3(
    const ushort* __restrict__ A, const ushort* __restrict__ Bt,
    const float* __restrict__ bias, const float* __restrict__ extra,
    ushort* __restrict__ outb, float* __restrict__ outf,
    int M, int N, int K, int nbx)
{
  __shared__ __align__(16) ushort Al[128*32];
  __shared__ __align__(16) ushort Bl[128*32];
  const int nwg = gridDim.x, cpx = nwg >> 3;
  const int bid = blockIdx.x;
  const int swz = (bid & 7)*cpx + (bid >> 3);
  const int m0 = (swz / nbx)*128, n0 = (swz % nbx)*128;
  const int tid = threadIdx.x, lane = tid & 63, wid = tid >> 6;
  const int wm = (wid&1)*64, wn = (wid>>1)*64;
  const int l15 = lane&15, l4 = lane>>4;
  f32x4 acc[4][4];
  #pragma unroll
  for (int i=0;i<4;i++)
    #pragma unroll
    for (int jx=0;jx<4;jx++){ acc[i][jx][0]=0.f; acc[i][jx][1]=0.f; acc[i][jx][2]=0.f; acc[i][jx][3]=0.f; }
  // staging: 512 16B-chunks per matrix, 2 per thread each; chunk ch -> row ch/4, col (ch&3)*8
  const int ch0 = tid, ch1 = 256 + tid;
  const ushort* a0p = A  + (size_t)(m0 + (ch0>>2))*K + (ch0&3)*8;
  const ushort* a1p = A  + (size_t)(m0 + (ch1>>2))*K + (ch1&3)*8;
  const ushort* b0p = Bt + (size_t)(n0 + (ch0>>2))*K + (ch0&3)*8;
  const ushort* b1p = Bt + (size_t)(n0 + (ch1>>2))*K + (ch1&3)*8;
  ushort* la0 = &Al[ch0*8]; ushort* la1 = &Al[ch1*8];
  ushort* lb0 = &Bl[ch0*8]; ushort* lb1 = &Bl[ch1*8];
  for (int k0=0; k0<K; k0+=32){
    __syncthreads();                      // prior iteration's reads complete
    gl2lds16(a0p + k0, la0);
    gl2lds16(a1p + k0, la1);
    gl2lds16(b0p + k0, lb0);
    gl2lds16(b1p + k0, lb1);
    __syncthreads();                      // staged data visible (vmcnt drained)
    short8 af[4], bfr[4];
    #pragma unroll
    for (int mi=0;mi<4;mi++) af[mi]  = *(const short8*)&Al[(wm + mi*16 + l15)*32 + l4*8];
    #pragma unroll
    for (int nj=0;nj<4;nj++) bfr[nj] = *(const short8*)&Bl[(wn + nj*16 + l15)*32 + l4*8];
    #pragma unroll
    for (int mi=0;mi<4;mi++)
      #pragma unroll
      for (int nj=0;nj<4;nj++)
        acc[mi][nj] = __builtin_amdgcn_mfma_f32_16x16x32_bf16(af[mi], bfr[nj], acc[mi][nj], 0,0,0);
  }
  #pragma unroll
  for (int mi=0;mi<4;mi++)
    #pragma unroll
    for (int nj=0;nj<4;nj++)
      #pragma unroll
      for (int j=0;j<4;j++){
        int row = m0 + wm + mi*16 + l4*4 + j;
        int col = n0 + wn + nj*16 + l15;
        float v = acc[mi][nj][j] + bias[col];
        if constexpr (EPI==0){ v += extra[(size_t)(row>>10)*N + col]; outb[(size_t)row*N+col] = f2bf(v); }
        else if constexpr (EPI==1){ v += extra[(size_t)row*N + col]; outf[(size_t)row*N+col] = v; }
        else { v = 0.5f*v*(1.f+erff(v*0.70710678118f)); outb[(size_t)row*N+col] = f2bf(v); }
      }
}

// ---------------- fused rel-position attention v3: XCD swizzle + K prefetch + aligned P ----------------
__global__ __launch_bounds__(256,3) void attn3(
    const ushort* __restrict__ qkv, const ushort* __restrict__ Er,
    const ushort* __restrict__ Vt, ushort* __restrict__ out)
{
  const int bid0 = blockIdx.x;
  const int bid = ((bid0 & 7) << 9) | (bid0 >> 3);   // 8 heads' worth of WGs per XCD
  const int rt = bid & 63, h = (bid>>6)&15, b = bid>>10;
  const int bh = b*16 + h;
  const int r0 = rt*16;
  const int tid = threadIdx.x, w = tid>>6, lane = tid&63;
  const int l15 = lane&15, l4 = lane>>4;

  __shared__ ushort RRF[17552];                      // 17 rows, stride 1033, skew-ready
  __shared__ __align__(16) ushort shp[4][16][88];    // P^T (phase 2) then O^T partials (phase 3)
  __shared__ float mlbuf[4][2][16];

  const size_t base = (size_t)b*1024*3072 + (size_t)h*64;
  const ushort* Qp = qkv + base;
  const ushort* Kp = qkv + base + 1024;
  const ushort* Vp = Vt + (size_t)bh*64*1024;

  if (tid < 16) RRF[(tid+1)*1033] = 0;

  short8 qa[2], qb[2];
  const int q1 = min(r0 + 16 + l15, 1023);
  #pragma unroll
  for (int ks=0; ks<2; ++ks){
    qa[ks] = *(const short8*)(Qp + (size_t)(r0 + l15)*3072 + ks*32 + l4*8);
    qb[ks] = *(const short8*)(Qp + (size_t)q1*3072 + ks*32 + l4*8);
  }

  // Phase 1: rel rows r0..r0+16 into RRF
  for (int t=0; t<16; ++t){
    const int et = w*16 + t;
    f32x4 a0 = {0.f,0.f,0.f,0.f}, a1 = {0.f,0.f,0.f,0.f};
    #pragma unroll
    for (int ks=0; ks<2; ++ks){
      short8 bfr = *(const short8*)(Er + (size_t)(et*16 + l15)*64 + ks*32 + l4*8);
      a0 = __builtin_amdgcn_mfma_f32_16x16x32_bf16(qa[ks], bfr, a0, 0,0,0);
      a1 = __builtin_amdgcn_mfma_f32_16x16x32_bf16(qb[ks], bfr, a1, 0,0,0);
    }
    const int e = et*16 + l15;
    #pragma unroll
    for (int j=0;j<4;j++) RRF[(l4*4+j)*1033 + 1 + e] = f2bf(a0[j]);
    if (l4 == 0) RRF[16*1033 + 1 + e] = f2bf(a1[0]);
  }
  __syncthreads();

  float m = -1e30f, lsum = 0.f;
  f32x4 Oacc[4];
  #pragma unroll
  for (int n2=0;n2<4;n2++){ Oacc[n2][0]=0.f; Oacc[n2][1]=0.f; Oacc[n2][2]=0.f; Oacc[n2][3]=0.f; }
  const int dl = 4*l4 - l15;
  const int rbase = l15*1033;
  const int c0base = w*256;

  // Phase 2: online softmax with K double-buffer; no barriers
  short8 ka[2][4][2];
  #pragma unroll
  for (int f=0;f<4;f++)
    #pragma unroll
    for (int ks=0;ks<2;ks++)
      ka[0][f][ks] = *(const short8*)(Kp + (size_t)(c0base + f*16 + l15)*3072 + ks*32 + l4*8);

  #pragma unroll
  for (int t=0;t<4;++t){
    const int cur = t&1;
    const int c0 = c0base + t*64;
    f32x4 S[4];
    #pragma unroll
    for (int f=0;f<4;f++){
      S[f][0]=0.f; S[f][1]=0.f; S[f][2]=0.f; S[f][3]=0.f;
      #pragma unroll
      for (int ks=0;ks<2;ks++)
        S[f] = __builtin_amdgcn_mfma_f32_16x16x32_bf16(ka[cur][f][ks], qa[ks], S[f], 0,0,0);
    }
    if (t < 3){
      const int c2 = c0 + 64;
      #pragma unroll
      for (int f=0;f<4;f++)
        #pragma unroll
        for (int ks=0;ks<2;ks++)
          ka[cur^1][f][ks] = *(const short8*)(Kp + (size_t)(c2 + f*16 + l15)*3072 + ks*32 + l4*8);
    }
    short8 va[2][4];
    #pragma unroll
    for (int ks=0;ks<2;ks++)
      #pragma unroll
      for (int n2=0;n2<4;n2++)
        va[ks][n2] = *(const short8*)(Vp + (size_t)(n2*16 + l15)*1024 + c0 + ks*32 + l4*8);
    // scale + skew + row-max (q-row = l15 per lane)
    float tmax = -3e30f;
    #pragma unroll
    for (int f=0;f<4;f++)
      #pragma unroll
      for (int j=0;j<4;j++){
        int d = (c0 + f*16 + j - r0) + dl;
        int off = (d<=0) ? (1024+d) : (1032+d);
        float v = fmaf(S[f][j], 0.125f, bf2f(RRF[rbase + off]));
        S[f][j] = v;
        tmax = fmaxf(tmax, v);
      }
    tmax = fmaxf(tmax, __shfl_xor(tmax, 16, 64));
    tmax = fmaxf(tmax, __shfl_xor(tmax, 32, 64));
    const float mn = fmaxf(m, tmax);
    const float scl = __expf(m - mn);
    m = mn;
    float tsum = 0.f;
    #pragma unroll
    for (int f=0;f<4;f++){
      float p0 = __expf(S[f][0]-m), p1 = __expf(S[f][1]-m), p2 = __expf(S[f][2]-m), p3 = __expf(S[f][3]-m);
      tsum += (p0+p1)+(p2+p3);
      ushort4 pw = make_ushort4(f2bf(p0), f2bf(p1), f2bf(p2), f2bf(p3));
      *(ushort4*)&shp[w][l15][f*16 + l4*4] = pw;
    }
    tsum += __shfl_xor(tsum, 16, 64);
    tsum += __shfl_xor(tsum, 32, 64);
    lsum = lsum*scl + tsum;
    #pragma unroll
    for (int n2=0;n2<4;n2++)
      #pragma unroll
      for (int j=0;j<4;j++) Oacc[n2][j] *= scl;
    #pragma unroll
    for (int ks=0; ks<2; ++ks){
      short8 pb = *(const short8*)&shp[w][l15][ks*32 + l4*8];
      #pragma unroll
      for (int n2=0; n2<4; ++n2)
        Oacc[n2] = __builtin_amdgcn_mfma_f32_16x16x32_bf16(va[ks][n2], pb, Oacc[n2], 0,0,0);
    }
  }

  // Phase 3: per-wave partials into shp (own region, same-wave reuse), then merge
  #pragma unroll
  for (int n2=0;n2<4;n2++){
    ushort4 ow = make_ushort4(f2bf(Oacc[n2][0]), f2bf(Oacc[n2][1]), f2bf(Oacc[n2][2]), f2bf(Oacc[n2][3]));
    *(ushort4*)&shp[w][l15][n2*16 + l4*4] = ow;
  }
  if (l4 == 0){ mlbuf[w][0][l15] = m; mlbuf[w][1][l15] = lsum; }
  __syncthreads();
  {
    const int row = tid>>4, hb = (tid&15)*4;
    float M2 = mlbuf[0][0][row];
    #pragma unroll
    for (int w2=1;w2<4;w2++) M2 = fmaxf(M2, mlbuf[w2][0][row]);
    float den = 0.f, num[4] = {0.f,0.f,0.f,0.f};
    #pragma unroll
    for (int w2=0;w2<4;w2++){
      float e = __expf(mlbuf[w2][0][row] - M2);
      den += mlbuf[w2][1][row]*e;
      ushort4 ov = *(const ushort4*)&shp[w2][row][hb];
      num[0] += bf2f(ov.x)*e; num[1] += bf2f(ov.y)*e; num[2] += bf2f(ov.z)*e; num[3] += bf2f(ov.w)*e;
    }
    float inv = 1.f/den;
    ushort4 u;
    u.x = f2bf(num[0]*inv); u.y = f2bf(num[1]*inv); u.z = f2bf(num[2]*inv); u.w = f2bf(num[3]*inv);
    *(ushort4*)&out[((size_t)(b*1024 + r0 + row))*1024 + h*64 + hb] = u;
  }
}

extern "C" void kernel_launch(void* const* d_in, const int* in_sizes, int n_in,
                              void* d_out, int out_size, void* d_ws, size_t ws_size,
                              hipStream_t stream)
{
  const float* x    = (const float*)d_in[0];
  const float* t    = (const float*)d_in[1];
  const float* ln1g = (const float*)d_in[2];
  const float* ln1b = (const float*)d_in[3];
  const float* qkvw = (const float*)d_in[4];
  const float* qkvb = (const float*)d_in[5];
  const float* timew= (const float*)d_in[6];
  const float* timeb= (const float*)d_in[7];
  const float* outw = (const float*)d_in[8];
  const float* outbv= (const float*)d_in[9];
  const float* Er   = (const float*)d_in[10];
  const float* ln2g = (const float*)d_in[11];
  const float* ln2b = (const float*)d_in[12];
  const float* ff1w = (const float*)d_in[13];
  const float* ff1b = (const float*)d_in[14];
  const float* ff2w = (const float*)d_in[15];
  const float* ff2b = (const float*)d_in[16];
  float* o = (float*)d_out;

  char* ws = (char*)d_ws;
  ushort* qkvw_t = (ushort*)(ws);              // [3072][1024]
  ushort* outw_t = (ushort*)(ws + 6291456);    // [1024][1024]
  ushort* ff1w_t = (ushort*)(ws + 8388608);    // [4096][1024]
  ushort* ff2w_t = (ushort*)(ws + 16777216);   // [1024][4096]
  ushort* er_b   = (ushort*)(ws + 25165824);   // [1024][64]
  float*  tq     = (float*) (ws + 25296896);   // [4][3072]
  ushort* bufA   = (ushort*)(ws + 25346048);   // 4096x1024 bf16: xn -> attn_out -> h
  ushort* vt     = (ushort*)(ws + 33734656);   // [64*64][1024] bf16 V-transposed
  ushort* bufB   = (ushort*)(ws + 42123264);   // qkv 4096x3072 / ff1o 4096x4096

  wt_cvt<<<dim3(48,16),256,0,stream>>>(qkvw, qkvw_t, 1024, 3072);
  wt_cvt<<<dim3(16,16),256,0,stream>>>(outw, outw_t, 1024, 1024);
  wt_cvt<<<dim3(64,16),256,0,stream>>>(ff1w, ff1w_t, 1024, 4096);
  wt_cvt<<<dim3(16,64),256,0,stream>>>(ff2w, ff2w_t, 4096, 1024);
  cvt_f2b<<<256,256,0,stream>>>(Er, er_b, 65536);

  ln_rows<<<4096,256,0,stream>>>(x, ln1g, ln1b, bufA);
  tq_gemm2<<<48,256,0,stream>>>(t, timew, timeb, tq);
  gemm3<0><<<768,256,0,stream>>>(bufA, qkvw_t, qkvb, tq, bufB, nullptr, 4096,3072,1024, 24);
  vt_k<<<dim3(16,64),256,0,stream>>>(bufB, vt);
  attn3<<<4096,256,0,stream>>>(bufB, er_b, vt, bufA);
  gemm3<1><<<256,256,0,stream>>>(bufA, outw_t, outbv, x, nullptr, o, 4096,1024,1024, 8);
  ln_rows<<<4096,256,0,stream>>>(o, ln2g, ln2b, bufA);
  gemm3<2><<<1024,256,0,stream>>>(bufA, ff1w_t, ff1b, nullptr, bufB, nullptr, 4096,4096,1024, 32);
  gemm3<1><<<256,256,0,stream>>>(bufB, ff2w_t, ff2b, o, nullptr, o, 4096,1024,4096, 8);
}